// Round 15
// baseline (774.159 us; speedup 1.0000x reference)
//
#include <hip/hip_runtime.h>
#include <hip/hip_bf16.h>
#include <hip/hip_fp16.h>

constexpr int Nn = 100000;
constexpr int Ee = 1200000;
constexpr int Ll = 5;
constexpr int Gg = 128;
constexpr int PDim = 320; // L*D
constexpr int GG = (Nn + 63) / 64; // 1563 gemm blocks

// bucketed CSR build params
constexpr int NB    = 98;     // buckets of 1024 rows (dst >> 10)
constexpr int BCAP  = 16384;  // per-bucket edge capacity
constexpr int CHUNK = 4096;   // edges per bin_edges block
constexpr int NBLK_A = (Ee + CHUNK - 1) / CHUNK; // 293

typedef float f32x4 __attribute__((ext_vector_type(4)));
typedef _Float16 half8 __attribute__((ext_vector_type(8)));

union U4H8 { uint4 u; half8 h; };

__device__ inline ushort f2h(float f) {
    const __half h = __float2half(f);
    return *(const ushort*)&h;
}
__device__ inline uint pack2h(float lo, float hi) {
    return (uint)f2h(lo) | ((uint)f2h(hi) << 16);
}
__device__ inline float h2f_lo(uint u) {
    const ushort s = (ushort)(u & 0xffffu);
    return __half2float(*(const __half*)&s);
}
__device__ inline float h2f_hi(uint u) {
    const ushort s = (ushort)(u >> 16);
    return __half2float(*(const __half*)&s);
}
__device__ inline float h2f(ushort s) {
    return __half2float(*(const __half*)&s);
}

__device__ inline int lower_bound_i(const int* __restrict__ a, int n, int v)
{
    int lo = 0, hi = n;
    while (lo < hi) {
        const int m = (lo + hi) >> 1;
        if (a[m] < v) lo = m + 1; else hi = m;
    }
    return lo;
}

// ---------------------------------------------------------------------------
// init: gCursor for buckets, per-graph node counts, identity BN sc.
// ---------------------------------------------------------------------------
__global__ void init_csr(const int* __restrict__ batch, int* __restrict__ gCursor,
                         int* __restrict__ cnt, float* __restrict__ sc)
{
    const int t = threadIdx.x; // 128
    if (t < NB) gCursor[t] = t * BCAP;
    {
        const int lo = lower_bound_i(batch, Nn, t);
        const int hi = lower_bound_i(batch, Nn, t + 1);
        cnt[t] = hi - lo;
    }
    if (t < 64) { sc[t] = 1.f; sc[64 + t] = 0.f; }
}

// ---------------------------------------------------------------------------
// Weight conversion: 11 64x64 f32 matrices -> TRANSPOSED fp16 hi + fp16
// (residual*2048) lo. 22-bit effective weight precision.
// Block m: 0=Ws, 1..5=W1[m-1], 6..10=W2[m-6].
// ---------------------------------------------------------------------------
__global__ __launch_bounds__(256) void conv_weights(
    const float* __restrict__ Ws, const float* __restrict__ W1,
    const float* __restrict__ W2, ushort* __restrict__ WThi,
    ushort* __restrict__ WTlo)
{
    const int m = blockIdx.x;
    const float* src = (m == 0) ? Ws
                     : (m <= 5) ? W1 + (size_t)(m - 1) * 4096
                                : W2 + (size_t)(m - 6) * 4096;
    ushort* dh = WThi + (size_t)m * 4096;
    ushort* dl = WTlo + (size_t)m * 4096;
    const int t = threadIdx.x;
    const int col = t & 63;
    const int k0 = (t >> 6) * 16;
    #pragma unroll
    for (int i = 0; i < 16; i++) {
        const int k = k0 + i;
        const float w = src[k * 64 + col];
        const ushort h = f2h(w);
        dh[col * 64 + k] = h;
        const float resid = (w - h2f(h)) * 2048.0f;
        dl[col * 64 + k] = f2h(resid);
    }
}

// ---------------------------------------------------------------------------
// Encoder GEMM (fp16 MFMA): Zs = fp16(x @ Ws + bs).
// ---------------------------------------------------------------------------
__global__ __launch_bounds__(256) void gemm_enc(
    const float* __restrict__ A1,
    const ushort* __restrict__ WThi, const ushort* __restrict__ WTlo,
    const float* __restrict__ bias, ushort* __restrict__ Ys)
{
    const int t = threadIdx.x;
    const int w = t >> 6;
    const int l = t & 63;
    const int lr = l & 15;
    const int lk = l >> 4;

    half8 bHi[4][2], bLo[4][2];
    #pragma unroll
    for (int nt = 0; nt < 4; nt++)
        #pragma unroll
        for (int c = 0; c < 2; c++) {
            const int off = (nt * 16 + lr) * 64 + c * 32 + lk * 8;
            U4H8 uh, ul;
            uh.u = *(const uint4*)(WThi + off);
            ul.u = *(const uint4*)(WTlo + off);
            bHi[nt][c] = uh.h;
            bLo[nt][c] = ul.h;
        }

    const int arow = blockIdx.x * 64 + w * 16 + lr;
    half8 aHi[2], aLo[2];
    if (arow < Nn) {
        #pragma unroll
        for (int c = 0; c < 2; c++) {
            const float* p1 = A1 + (size_t)arow * 64 + c * 32 + lk * 8;
            U4H8 rh, rl;
            #pragma unroll
            for (int i = 0; i < 8; i++) {
                const float xv = p1[i];
                const _Float16 xh = (_Float16)xv;
                rh.h[i] = xh;
                rl.h[i] = (_Float16)((xv - (float)xh) * 2048.0f);
            }
            aHi[c] = rh.h;
            aLo[c] = rl.h;
        }
    } else {
        U4H8 z; z.u = make_uint4(0, 0, 0, 0);
        aHi[0] = aHi[1] = z.h;
        aLo[0] = aLo[1] = z.h;
    }

    f32x4 accH[4] = {}, accL[4] = {};
    #pragma unroll
    for (int nt = 0; nt < 4; nt++)
        #pragma unroll
        for (int c = 0; c < 2; c++) {
            accH[nt] = __builtin_amdgcn_mfma_f32_16x16x32_f16(
                aHi[c], bHi[nt][c], accH[nt], 0, 0, 0);
            accL[nt] = __builtin_amdgcn_mfma_f32_16x16x32_f16(
                aHi[c], bLo[nt][c], accL[nt], 0, 0, 0);
            accL[nt] = __builtin_amdgcn_mfma_f32_16x16x32_f16(
                aLo[c], bHi[nt][c], accL[nt], 0, 0, 0);
        }

    #pragma unroll
    for (int nt = 0; nt < 4; nt++) {
        const int ccol = nt * 16 + lr;
        const float bb = bias[ccol];
        #pragma unroll
        for (int j = 0; j < 4; j++) {
            const int crow = blockIdx.x * 64 + w * 16 + lk * 4 + j;
            if (crow < Nn)
                Ys[(size_t)crow * 64 + ccol] =
                    f2h(fmaf(accL[nt][j], 1.0f / 2048.0f, accH[nt][j]) + bb);
        }
    }
}

// ---------------------------------------------------------------------------
// Fused GIN MLP (fp16 MFMA): Zs = fp16(relu(relu(u@W1+b1)@W2+b2)).
// Per-column BN stats -> per-block PARTIAL writes (spart[blk][128]).
// spart[blk][0:64] doubles as the block's raw-z column sum (used by
// reduce_pool). M in LDS fp16 [64][72].
// ---------------------------------------------------------------------------
__global__ __launch_bounds__(256) void fused_mlp(
    const ushort* __restrict__ Us,
    const ushort* __restrict__ WT1hi, const ushort* __restrict__ WT1lo,
    const float* __restrict__ b1v,
    const ushort* __restrict__ WT2hi, const ushort* __restrict__ WT2lo,
    const float* __restrict__ b2v,
    ushort* __restrict__ Zs, float* __restrict__ spart)
{
    const int t = threadIdx.x;
    const int w = t >> 6;
    const int l = t & 63;
    const int lr = l & 15;   // A-row / B-col within 16-tile
    const int lk = l >> 4;   // k-group (8 elems each)

    __shared__ ushort Mh[64][72];
    __shared__ float red[2][4][4][16];

    // ---- stage 1: M = relu(u @ W1 + b1) ----
    half8 b1Hi[4][2], b1Lo[4][2];
    #pragma unroll
    for (int nt = 0; nt < 4; nt++)
        #pragma unroll
        for (int c = 0; c < 2; c++) {
            const int off = (nt * 16 + lr) * 64 + c * 32 + lk * 8;
            U4H8 uh, ul;
            uh.u = *(const uint4*)(WT1hi + off);
            ul.u = *(const uint4*)(WT1lo + off);
            b1Hi[nt][c] = uh.h;
            b1Lo[nt][c] = ul.h;
        }

    const int arow = blockIdx.x * 64 + w * 16 + lr;
    half8 aF[2];
    if (arow < Nn) {
        U4H8 v0, v1;
        v0.u = *(const uint4*)(Us + (size_t)arow * 64 + lk * 8);
        v1.u = *(const uint4*)(Us + (size_t)arow * 64 + 32 + lk * 8);
        aF[0] = v0.h;
        aF[1] = v1.h;
    } else {
        U4H8 z; z.u = make_uint4(0, 0, 0, 0);
        aF[0] = aF[1] = z.h;
    }

    f32x4 accH[4] = {}, accL[4] = {};
    #pragma unroll
    for (int nt = 0; nt < 4; nt++)
        #pragma unroll
        for (int c = 0; c < 2; c++) {
            accH[nt] = __builtin_amdgcn_mfma_f32_16x16x32_f16(
                aF[c], b1Hi[nt][c], accH[nt], 0, 0, 0);
            accL[nt] = __builtin_amdgcn_mfma_f32_16x16x32_f16(
                aF[c], b1Lo[nt][c], accL[nt], 0, 0, 0);
        }

    // M -> LDS (fp16); C/D layout: row = lk*4+j, col = nt*16+lr [m89]
    #pragma unroll
    for (int nt = 0; nt < 4; nt++) {
        const int ccol = nt * 16 + lr;
        const float bb = b1v[ccol];
        #pragma unroll
        for (int j = 0; j < 4; j++) {
            const int rloc = w * 16 + lk * 4 + j;
            const float m = fmaxf(fmaf(accL[nt][j], 1.0f / 2048.0f, accH[nt][j]) + bb, 0.f);
            Mh[rloc][ccol] = f2h(m);
        }
    }
    __syncthreads();

    // ---- stage 2: z = relu(M @ W2 + b2) ----
    half8 b2Hi[4][2], b2Lo[4][2];
    #pragma unroll
    for (int nt = 0; nt < 4; nt++)
        #pragma unroll
        for (int c = 0; c < 2; c++) {
            const int off = (nt * 16 + lr) * 64 + c * 32 + lk * 8;
            U4H8 uh, ul;
            uh.u = *(const uint4*)(WT2hi + off);
            ul.u = *(const uint4*)(WT2lo + off);
            b2Hi[nt][c] = uh.h;
            b2Lo[nt][c] = ul.h;
        }

    half8 a2F[2];
    #pragma unroll
    for (int c = 0; c < 2; c++) {
        U4H8 v;
        v.u = *(const uint4*)&Mh[w * 16 + lr][c * 32 + lk * 8];
        a2F[c] = v.h;
    }

    f32x4 acc2H[4] = {}, acc2L[4] = {};
    #pragma unroll
    for (int nt = 0; nt < 4; nt++)
        #pragma unroll
        for (int c = 0; c < 2; c++) {
            acc2H[nt] = __builtin_amdgcn_mfma_f32_16x16x32_f16(
                a2F[c], b2Hi[nt][c], acc2H[nt], 0, 0, 0);
            acc2L[nt] = __builtin_amdgcn_mfma_f32_16x16x32_f16(
                a2F[c], b2Lo[nt][c], acc2L[nt], 0, 0, 0);
        }

    float s[4], s2[4];
    #pragma unroll
    for (int nt = 0; nt < 4; nt++) {
        const int ccol = nt * 16 + lr;
        const float bb = b2v[ccol];
        s[nt] = 0.f; s2[nt] = 0.f;
        #pragma unroll
        for (int j = 0; j < 4; j++) {
            const int crow = blockIdx.x * 64 + w * 16 + lk * 4 + j;
            if (crow < Nn) {
                const float v = fmaxf(fmaf(acc2L[nt][j], 1.0f / 2048.0f, acc2H[nt][j]) + bb, 0.f);
                Zs[(size_t)crow * 64 + ccol] = f2h(v);
                s[nt] += v; s2[nt] += v * v;
            }
        }
    }

    #pragma unroll
    for (int nt = 0; nt < 4; nt++) {
        s[nt]  += __shfl_xor(s[nt], 16);  s[nt]  += __shfl_xor(s[nt], 32);
        s2[nt] += __shfl_xor(s2[nt], 16); s2[nt] += __shfl_xor(s2[nt], 32);
    }
    if (l < 16) {
        #pragma unroll
        for (int nt = 0; nt < 4; nt++) {
            red[0][w][nt][l] = s[nt];
            red[1][w][nt][l] = s2[nt];
        }
    }
    __syncthreads();
    if (t < 64) { // column = (t>>4)*16 + (t&15) = t
        float ts = 0.f, ts2 = 0.f;
        #pragma unroll
        for (int wv = 0; wv < 4; wv++) {
            ts  += red[0][wv][t >> 4][t & 15];
            ts2 += red[1][wv][t >> 4][t & 15];
        }
        // coalesced per-block partial write (no atomics)
        spart[(size_t)blockIdx.x * 128 + t] = ts;
        spart[(size_t)blockIdx.x * 128 + 64 + t] = ts2;
    }
}

// ---------------------------------------------------------------------------
// Reduce per-block stats partials (atomic-free): sp16[b][c] = partial sums.
// 16 blocks x 128 threads.
// ---------------------------------------------------------------------------
__global__ __launch_bounds__(128) void reduce_stats(
    const float* __restrict__ spart, float* __restrict__ sp16)
{
    const int t = threadIdx.x; // 0..127
    const int r0 = blockIdx.x * 98;
    const int r1 = min(r0 + 98, GG);
    float acc = 0.f;
    for (int r = r0; r < r1; r++)
        acc += spart[(size_t)r * 128 + t];
    sp16[(size_t)blockIdx.x * 128 + t] = acc;
}

// Compute scale/shift from sp16 -> sc (current) + sc5[layer].
__global__ void bn_finalize(
    const float* __restrict__ sp16, const float* __restrict__ gamma,
    const float* __restrict__ beta, float* __restrict__ sc,
    float* __restrict__ sc5, int layer)
{
    const int c = threadIdx.x; // 64 threads, 1 block
    float sum = 0.f, sum2 = 0.f;
    #pragma unroll
    for (int b = 0; b < 16; b++) {
        sum  += sp16[b * 128 + c];
        sum2 += sp16[b * 128 + 64 + c];
    }
    const float mean = sum * (1.0f / Nn);
    const float var = sum2 * (1.0f / Nn) - mean * mean;
    const float scale = gamma[layer * 64 + c] * rsqrtf(var + 1e-5f);
    const float shift = beta[layer * 64 + c] - mean * scale;
    sc[c] = scale;
    sc[64 + c] = shift;
    sc5[layer * 128 + c] = scale;
    sc5[layer * 128 + 64 + c] = shift;
}

// ---------------------------------------------------------------------------
// Per-graph raw-z sums from spart (full blocks) + Zs (boundary rows).
// One block (64 threads) per graph. Writes poolZ[g][c] (no atomics).
// ---------------------------------------------------------------------------
__global__ __launch_bounds__(64) void reduce_pool(
    const float* __restrict__ spart, const ushort* __restrict__ zs,
    const int* __restrict__ batch, float* __restrict__ poolZ)
{
    const int g = blockIdx.x;
    const int c = threadIdx.x; // 0..63
    const int lo = lower_bound_i(batch, Nn, g);
    const int hi = lower_bound_i(batch, Nn, g + 1);
    const int bs = (lo + 63) >> 6;  // first full block
    const int be = hi >> 6;         // one past last full block
    float acc = 0.f;
    if (bs <= be) {
        for (int b = bs; b < be; b++)
            acc += spart[(size_t)b * 128 + c];
        for (int r = lo; r < bs * 64; r++)
            acc += h2f(zs[(size_t)r * 64 + c]);
        for (int r = be * 64; r < hi; r++)
            acc += h2f(zs[(size_t)r * 64 + c]);
    } else {
        for (int r = lo; r < hi; r++)
            acc += h2f(zs[(size_t)r * 64 + c]);
    }
    poolZ[g * 64 + c] = acc;
}

// ---------------------------------------------------------------------------
// Bucketed CSR build.
// ---------------------------------------------------------------------------
__global__ __launch_bounds__(256) void bin_edges(
    const int* __restrict__ ei, int* __restrict__ gCursor,
    uint2* __restrict__ binned)
{
    __shared__ int hist[NB];
    __shared__ int base[NB];
    __shared__ int cur[NB];
    const int t = threadIdx.x;
    const int e0 = blockIdx.x * CHUNK;
    const int eEnd = min(e0 + CHUNK, Ee);
    if (t < NB) hist[t] = 0;
    __syncthreads();
    for (int e = e0 + t; e < eEnd; e += 256)
        atomicAdd(&hist[ei[Ee + e] >> 10], 1);
    __syncthreads();
    if (t < NB) {
        base[t] = atomicAdd(&gCursor[t], hist[t]);
        cur[t] = 0;
    }
    __syncthreads();
    for (int e = e0 + t; e < eEnd; e += 256) {
        const int s = ei[e];
        const int d = ei[Ee + e];
        const int b = d >> 10;
        const int pos = atomicAdd(&cur[b], 1);
        binned[(size_t)base[b] + pos] = make_uint2((uint)d, (uint)s);
    }
}

__global__ __launch_bounds__(128) void scan_buckets(
    const int* __restrict__ gCursor, int* __restrict__ bucketBase)
{
    __shared__ int sh[128];
    const int t = threadIdx.x;
    const int c = (t < NB) ? gCursor[t] - t * BCAP : 0;
    sh[t] = c;
    __syncthreads();
    for (int off = 1; off < 128; off <<= 1) {
        const int u = (t >= off) ? sh[t - off] : 0;
        __syncthreads();
        sh[t] += u;
        __syncthreads();
    }
    bucketBase[t] = sh[t] - c; // exclusive
}

__global__ __launch_bounds__(256) void build_csr(
    const uint2* __restrict__ binned, const int* __restrict__ gCursor,
    const int* __restrict__ bucketBase, int* __restrict__ rowptr,
    int* __restrict__ colidx)
{
    __shared__ int degS[1024];
    __shared__ int sh[256];
    __shared__ int colStage[BCAP];
    const int b = blockIdx.x;
    const int t = threadIdx.x;
    const int cnt = gCursor[b] - b * BCAP;
    const int base = bucketBase[b];
    const uint2* src = binned + (size_t)b * BCAP;

    for (int i = t; i < 1024; i += 256) degS[i] = 0;
    __syncthreads();
    for (int i = t; i < cnt; i += 256)
        atomicAdd(&degS[src[i].x & 1023], 1);
    __syncthreads();

    const int b4 = t * 4;
    const int v0 = degS[b4], v1 = degS[b4 + 1], v2 = degS[b4 + 2], v3 = degS[b4 + 3];
    const int sSum = v0 + v1 + v2 + v3;
    sh[t] = sSum;
    __syncthreads();
    for (int off = 1; off < 256; off <<= 1) {
        const int u = (t >= off) ? sh[t - off] : 0;
        __syncthreads();
        sh[t] += u;
        __syncthreads();
    }
    const int excl = sh[t] - sSum;
    const int p0 = excl, p1 = excl + v0, p2 = excl + v0 + v1, p3 = excl + v0 + v1 + v2;

    const int grow = b * 1024 + b4;
    if (grow + 3 <= Nn) {
        *(int4*)(rowptr + grow) = make_int4(base + p0, base + p1, base + p2, base + p3);
    } else {
        if (grow + 0 <= Nn) rowptr[grow + 0] = base + p0;
        if (grow + 1 <= Nn) rowptr[grow + 1] = base + p1;
        if (grow + 2 <= Nn) rowptr[grow + 2] = base + p2;
        if (grow + 3 <= Nn) rowptr[grow + 3] = base + p3;
    }

    degS[b4] = p0; degS[b4 + 1] = p1; degS[b4 + 2] = p2; degS[b4 + 3] = p3;
    __syncthreads();
    for (int i = t; i < cnt; i += 256) {
        const uint2 p = src[i];
        const int pos = atomicAdd(&degS[p.x & 1023], 1);
        colStage[pos] = (int)p.y;
    }
    __syncthreads();
    for (int i = t; i < cnt; i += 256) colidx[base + i] = colStage[i];
}

// ---------------------------------------------------------------------------
// Gather + deferred BN: u[r] = scale ∘ (z[r] + Σ_{j∈N(r)} z[j]) + (1+deg)*shift.
// 8-way unrolled independent gathers for memory-level parallelism.
// z fp16 in, u fp16 out, affine in f32. 8 lanes per row, 32 rows per block.
// ---------------------------------------------------------------------------
__global__ __launch_bounds__(256) void gather_bn(
    const int* __restrict__ rowptr, const int* __restrict__ col,
    const ushort* __restrict__ zs, const float* __restrict__ sc,
    ushort* __restrict__ us)
{
    __shared__ float scS[128];
    const int t = threadIdx.x;
    if (t < 128) scS[t] = sc[t];
    __syncthreads();

    const int r = blockIdx.x * 32 + (t >> 3);
    const int q = t & 7;
    const int beg = rowptr[r], end = rowptr[r + 1];
    float a[8];
    {
        const uint4 v = *(const uint4*)(zs + (size_t)r * 64 + q * 8); // self
        a[0] = h2f_lo(v.x); a[1] = h2f_hi(v.x);
        a[2] = h2f_lo(v.y); a[3] = h2f_hi(v.y);
        a[4] = h2f_lo(v.z); a[5] = h2f_hi(v.z);
        a[6] = h2f_lo(v.w); a[7] = h2f_hi(v.w);
    }
    int j = beg;
    const int end8 = beg + ((end - beg) & ~7);
    for (; j < end8; j += 8) {
        uint4 v[8];
        #pragma unroll
        for (int k = 0; k < 8; k++) {
            const int s = col[j + k];
            v[k] = *(const uint4*)(zs + (size_t)s * 64 + q * 8);
        }
        #pragma unroll
        for (int k = 0; k < 8; k++) {
            a[0] += h2f_lo(v[k].x); a[1] += h2f_hi(v[k].x);
            a[2] += h2f_lo(v[k].y); a[3] += h2f_hi(v[k].y);
            a[4] += h2f_lo(v[k].z); a[5] += h2f_hi(v[k].z);
            a[6] += h2f_lo(v[k].w); a[7] += h2f_hi(v[k].w);
        }
    }
    for (; j < end; j++) {
        const int s = col[j];
        const uint4 v = *(const uint4*)(zs + (size_t)s * 64 + q * 8);
        a[0] += h2f_lo(v.x); a[1] += h2f_hi(v.x);
        a[2] += h2f_lo(v.y); a[3] += h2f_hi(v.y);
        a[4] += h2f_lo(v.z); a[5] += h2f_hi(v.z);
        a[6] += h2f_lo(v.w); a[7] += h2f_hi(v.w);
    }
    const float dgf = (float)(end - beg + 1);
    float o[8];
    #pragma unroll
    for (int i = 0; i < 8; i++)
        o[i] = fmaf(scS[q * 8 + i], a[i], dgf * scS[64 + q * 8 + i]);
    uint4 p;
    p.x = pack2h(o[0], o[1]); p.y = pack2h(o[2], o[3]);
    p.z = pack2h(o[4], o[5]); p.w = pack2h(o[6], o[7]);
    *(uint4*)(us + (size_t)r * 64 + q * 8) = p;
}

// ---------------------------------------------------------------------------
// Final pooled transform across all layers:
// pooled[g][l*64+c] = sc5[l][c]*poolZ[l][g][c] + cnt[g]*sc5[l][64+c]
// ---------------------------------------------------------------------------
__global__ __launch_bounds__(256) void final_pool(
    const float* __restrict__ sc5, const float* __restrict__ poolZ,
    const int* __restrict__ cnt, float* __restrict__ pooled)
{
    const int idx = blockIdx.x * 256 + threadIdx.x; // 40960
    const int c = idx & 63;
    const int g = (idx >> 6) & 127;
    const int l = idx >> 13;
    pooled[g * PDim + l * 64 + c] =
        sc5[l * 128 + c] * poolZ[(size_t)l * Gg * 64 + g * 64 + c]
        + (float)cnt[g] * sc5[l * 128 + 64 + c];
}

// ---------------------------------------------------------------------------
// Proj head GEMM: (128,320)@(320,320)+b (f32, small).
// ---------------------------------------------------------------------------
template<bool RELU>
__global__ __launch_bounds__(256) void proj(
    const float* __restrict__ X, const float* __restrict__ W,
    const float* __restrict__ bias, float* __restrict__ Y)
{
    const int idx = blockIdx.x * 256 + threadIdx.x; // 40960 exact
    const int r = idx / PDim;
    const int c = idx - r * PDim;
    float acc = bias[c];
    #pragma unroll 8
    for (int k = 0; k < PDim; k++)
        acc = fmaf(X[r * PDim + k], W[k * PDim + c], acc);
    if constexpr (RELU) acc = fmaxf(acc, 0.f);
    Y[idx] = acc;
}

// ---------------------------------------------------------------------------
// Row-wise l2 normalize.
// ---------------------------------------------------------------------------
__global__ __launch_bounds__(64) void l2norm_rows(
    const float* __restrict__ X, float* __restrict__ out)
{
    const int r = blockIdx.x;
    const int l = threadIdx.x;
    float v[5];
    float s = 0.f;
    #pragma unroll
    for (int i = 0; i < 5; i++) {
        v[i] = X[r * PDim + i * 64 + l];
        s += v[i] * v[i];
    }
    #pragma unroll
    for (int off = 32; off > 0; off >>= 1) s += __shfl_down(s, off);
    s = __shfl(s, 0);
    const float d = fmaxf(sqrtf(s), 1e-12f);
    #pragma unroll
    for (int i = 0; i < 5; i++)
        out[r * PDim + i * 64 + l] = v[i] / d;
}

// ---------------------------------------------------------------------------
extern "C" void kernel_launch(void* const* d_in, const int* in_sizes, int n_in,
                              void* d_out, int out_size, void* d_ws, size_t ws_size,
                              hipStream_t stream)
{
    const float* x     = (const float*)d_in[0];
    const int*   ei    = (const int*)d_in[1];
    const int*   batch = (const int*)d_in[2];
    const float* Ws    = (const float*)d_in[3];
    const float* bs    = (const float*)d_in[4];
    const float* W1    = (const float*)d_in[5];
    const float* b1    = (const float*)d_in[6];
    const float* W2    = (const float*)d_in[7];
    const float* b2    = (const float*)d_in[8];
    const float* gamma = (const float*)d_in[9];
    const float* beta  = (const float*)d_in[10];
    const float* Wp1   = (const float*)d_in[11];
    const float* bp1   = (const float*)d_in[12];
    const float* Wp2   = (const float*)d_in[13];
    const float* bp2   = (const float*)d_in[14];
    float* out = (float*)d_out;

    // workspace
    ushort* Us = (ushort*)d_ws;                   // u  fp16 (N*64)  12.8MB
    ushort* Zs = Us + (size_t)Nn * 64;            // z  fp16         12.8MB
    ushort* WThi = Zs + (size_t)Nn * 64;          // 11*4096 fp16
    ushort* WTlo = WThi + 11 * 4096;
    float* pooled = (float*)(WTlo + 11 * 4096);   // (G,320)
    float* ytmp   = pooled + (size_t)Gg * PDim;
    float* ypro   = ytmp + (size_t)Gg * PDim;
    float* sp16   = ypro + (size_t)Gg * PDim;     // 16*128
    float* sc     = sp16 + 16 * 128;              // 128
    float* sc5    = sc + 128;                     // 5*128
    float* poolZ  = sc5 + 5 * 128;                // 5*G*64
    float* spart  = poolZ + 5 * Gg * 64;          // GG*128 (800KB)
    int* cnt    = (int*)(spart + (size_t)GG * 128); // 128
    int* rowptr = cnt + 128;                      // Nn+1
    int* colidx = rowptr + Nn + 1;                // Ee
    int* gCursor = colidx + Ee;                   // 128 (NB used)
    int* bucketBase = gCursor + 128;              // 128
    size_t woff = (size_t)((bucketBase + 128) - (int*)d_ws);
    woff = (woff + 1) & ~(size_t)1;
    uint2* binned = (uint2*)((int*)d_ws + woff);  // NB*BCAP*8B = 12.6MB

    init_csr<<<1, 128, 0, stream>>>(batch, gCursor, cnt, sc);
    conv_weights<<<11, 256, 0, stream>>>(Ws, W1, W2, WThi, WTlo);

    // bucketed CSR build
    bin_edges<<<NBLK_A, 256, 0, stream>>>(ei, gCursor, binned);
    scan_buckets<<<1, 128, 0, stream>>>(gCursor, bucketBase);
    build_csr<<<NB, 256, 0, stream>>>(binned, gCursor, bucketBase, rowptr, colidx);

    // encoder: Zs = fp16(x @ Ws + bs)   (raw z_0; BN identity in sc)
    gemm_enc<<<GG, 256, 0, stream>>>(x, WThi, WTlo, bs, Zs);

    for (int l = 0; l < Ll; l++) {
        // u = BN_{l-1} applied to inclusive sum of raw z (affine distributes)
        gather_bn<<<Nn / 32, 256, 0, stream>>>(rowptr, colidx, Zs, sc, Us);
        fused_mlp<<<GG, 256, 0, stream>>>(
            Us,
            WThi + (size_t)(1 + l) * 4096, WTlo + (size_t)(1 + l) * 4096,
            b1 + (size_t)l * 64,
            WThi + (size_t)(6 + l) * 4096, WTlo + (size_t)(6 + l) * 4096,
            b2 + (size_t)l * 64,
            Zs, spart);
        reduce_stats<<<16, 128, 0, stream>>>(spart, sp16);
        bn_finalize<<<1, 64, 0, stream>>>(sp16, gamma, beta, sc, sc5, l);
        reduce_pool<<<Gg, 64, 0, stream>>>(spart, Zs, batch,
                                           poolZ + (size_t)l * Gg * 64);
    }

    final_pool<<<160, 256, 0, stream>>>(sc5, poolZ, cnt, pooled);

    // proj head (f32)
    proj<true><<<160, 256, 0, stream>>>(pooled, Wp1, bp1, ytmp);
    proj<false><<<160, 256, 0, stream>>>(ytmp, Wp2, bp2, ypro);

    l2norm_rows<<<Gg, 64, 0, stream>>>(ypro, out);               // out0
    l2norm_rows<<<Gg, 64, 0, stream>>>(pooled, out + Gg * PDim); // out1
}

// Round 16
// 748.861 us; speedup vs baseline: 1.0338x; 1.0338x over previous
//
#include <hip/hip_runtime.h>
#include <hip/hip_bf16.h>
#include <hip/hip_fp16.h>

constexpr int Nn = 100000;
constexpr int Ee = 1200000;
constexpr int Ll = 5;
constexpr int Gg = 128;
constexpr int PDim = 320; // L*D
constexpr int GG = (Nn + 63) / 64; // 1563 gemm blocks

// bucketed CSR build params
constexpr int NB    = 98;     // buckets of 1024 rows (dst >> 10)
constexpr int BCAP  = 16384;  // per-bucket edge capacity
constexpr int CHUNK = 4096;   // edges per bin_edges block
constexpr int NBLK_A = (Ee + CHUNK - 1) / CHUNK; // 293

typedef float f32x4 __attribute__((ext_vector_type(4)));
typedef _Float16 half8 __attribute__((ext_vector_type(8)));

union U4H8 { uint4 u; half8 h; };

__device__ inline ushort f2h(float f) {
    const __half h = __float2half(f);
    return *(const ushort*)&h;
}
__device__ inline uint pack2h(float lo, float hi) {
    return (uint)f2h(lo) | ((uint)f2h(hi) << 16);
}
__device__ inline float h2f_lo(uint u) {
    const ushort s = (ushort)(u & 0xffffu);
    return __half2float(*(const __half*)&s);
}
__device__ inline float h2f_hi(uint u) {
    const ushort s = (ushort)(u >> 16);
    return __half2float(*(const __half*)&s);
}
__device__ inline float h2f(ushort s) {
    return __half2float(*(const __half*)&s);
}

__device__ inline int lower_bound_i(const int* __restrict__ a, int n, int v)
{
    int lo = 0, hi = n;
    while (lo < hi) {
        const int m = (lo + hi) >> 1;
        if (a[m] < v) lo = m + 1; else hi = m;
    }
    return lo;
}

// ---------------------------------------------------------------------------
// init: gCursor for buckets, per-graph node counts, identity BN sc.
// ---------------------------------------------------------------------------
__global__ void init_csr(const int* __restrict__ batch, int* __restrict__ gCursor,
                         int* __restrict__ cnt, float* __restrict__ sc)
{
    const int t = threadIdx.x; // 128
    if (t < NB) gCursor[t] = t * BCAP;
    {
        const int lo = lower_bound_i(batch, Nn, t);
        const int hi = lower_bound_i(batch, Nn, t + 1);
        cnt[t] = hi - lo;
    }
    if (t < 64) { sc[t] = 1.f; sc[64 + t] = 0.f; }
}

// ---------------------------------------------------------------------------
// Weight conversion: 11 64x64 f32 matrices -> TRANSPOSED fp16 hi + fp16
// (residual*2048) lo. 22-bit effective weight precision.
// Block m: 0=Ws, 1..5=W1[m-1], 6..10=W2[m-6].
// ---------------------------------------------------------------------------
__global__ __launch_bounds__(256) void conv_weights(
    const float* __restrict__ Ws, const float* __restrict__ W1,
    const float* __restrict__ W2, ushort* __restrict__ WThi,
    ushort* __restrict__ WTlo)
{
    const int m = blockIdx.x;
    const float* src = (m == 0) ? Ws
                     : (m <= 5) ? W1 + (size_t)(m - 1) * 4096
                                : W2 + (size_t)(m - 6) * 4096;
    ushort* dh = WThi + (size_t)m * 4096;
    ushort* dl = WTlo + (size_t)m * 4096;
    const int t = threadIdx.x;
    const int col = t & 63;
    const int k0 = (t >> 6) * 16;
    #pragma unroll
    for (int i = 0; i < 16; i++) {
        const int k = k0 + i;
        const float w = src[k * 64 + col];
        const ushort h = f2h(w);
        dh[col * 64 + k] = h;
        const float resid = (w - h2f(h)) * 2048.0f;
        dl[col * 64 + k] = f2h(resid);
    }
}

// ---------------------------------------------------------------------------
// Encoder GEMM (fp16 MFMA): Zs = fp16(x @ Ws + bs).
// ---------------------------------------------------------------------------
__global__ __launch_bounds__(256) void gemm_enc(
    const float* __restrict__ A1,
    const ushort* __restrict__ WThi, const ushort* __restrict__ WTlo,
    const float* __restrict__ bias, ushort* __restrict__ Ys)
{
    const int t = threadIdx.x;
    const int w = t >> 6;
    const int l = t & 63;
    const int lr = l & 15;
    const int lk = l >> 4;

    half8 bHi[4][2], bLo[4][2];
    #pragma unroll
    for (int nt = 0; nt < 4; nt++)
        #pragma unroll
        for (int c = 0; c < 2; c++) {
            const int off = (nt * 16 + lr) * 64 + c * 32 + lk * 8;
            U4H8 uh, ul;
            uh.u = *(const uint4*)(WThi + off);
            ul.u = *(const uint4*)(WTlo + off);
            bHi[nt][c] = uh.h;
            bLo[nt][c] = ul.h;
        }

    const int arow = blockIdx.x * 64 + w * 16 + lr;
    half8 aHi[2], aLo[2];
    if (arow < Nn) {
        #pragma unroll
        for (int c = 0; c < 2; c++) {
            const float* p1 = A1 + (size_t)arow * 64 + c * 32 + lk * 8;
            U4H8 rh, rl;
            #pragma unroll
            for (int i = 0; i < 8; i++) {
                const float xv = p1[i];
                const _Float16 xh = (_Float16)xv;
                rh.h[i] = xh;
                rl.h[i] = (_Float16)((xv - (float)xh) * 2048.0f);
            }
            aHi[c] = rh.h;
            aLo[c] = rl.h;
        }
    } else {
        U4H8 z; z.u = make_uint4(0, 0, 0, 0);
        aHi[0] = aHi[1] = z.h;
        aLo[0] = aLo[1] = z.h;
    }

    f32x4 accH[4] = {}, accL[4] = {};
    #pragma unroll
    for (int nt = 0; nt < 4; nt++)
        #pragma unroll
        for (int c = 0; c < 2; c++) {
            accH[nt] = __builtin_amdgcn_mfma_f32_16x16x32_f16(
                aHi[c], bHi[nt][c], accH[nt], 0, 0, 0);
            accL[nt] = __builtin_amdgcn_mfma_f32_16x16x32_f16(
                aHi[c], bLo[nt][c], accL[nt], 0, 0, 0);
            accL[nt] = __builtin_amdgcn_mfma_f32_16x16x32_f16(
                aLo[c], bHi[nt][c], accL[nt], 0, 0, 0);
        }

    #pragma unroll
    for (int nt = 0; nt < 4; nt++) {
        const int ccol = nt * 16 + lr;
        const float bb = bias[ccol];
        #pragma unroll
        for (int j = 0; j < 4; j++) {
            const int crow = blockIdx.x * 64 + w * 16 + lk * 4 + j;
            if (crow < Nn)
                Ys[(size_t)crow * 64 + ccol] =
                    f2h(fmaf(accL[nt][j], 1.0f / 2048.0f, accH[nt][j]) + bb);
        }
    }
}

// ---------------------------------------------------------------------------
// Fused GIN MLP (fp16 MFMA): Zs = fp16(relu(relu(u@W1+b1)@W2+b2)).
// Per-column BN stats -> per-block PARTIAL writes (spart[blk][128]).
// spart[blk][0:64] doubles as the block's raw-z column sum (used by
// reduce_pool). M in LDS fp16 [64][72].
// ---------------------------------------------------------------------------
__global__ __launch_bounds__(256) void fused_mlp(
    const ushort* __restrict__ Us,
    const ushort* __restrict__ WT1hi, const ushort* __restrict__ WT1lo,
    const float* __restrict__ b1v,
    const ushort* __restrict__ WT2hi, const ushort* __restrict__ WT2lo,
    const float* __restrict__ b2v,
    ushort* __restrict__ Zs, float* __restrict__ spart)
{
    const int t = threadIdx.x;
    const int w = t >> 6;
    const int l = t & 63;
    const int lr = l & 15;   // A-row / B-col within 16-tile
    const int lk = l >> 4;   // k-group (8 elems each)

    __shared__ ushort Mh[64][72];
    __shared__ float red[2][4][4][16];

    // ---- stage 1: M = relu(u @ W1 + b1) ----
    half8 b1Hi[4][2], b1Lo[4][2];
    #pragma unroll
    for (int nt = 0; nt < 4; nt++)
        #pragma unroll
        for (int c = 0; c < 2; c++) {
            const int off = (nt * 16 + lr) * 64 + c * 32 + lk * 8;
            U4H8 uh, ul;
            uh.u = *(const uint4*)(WT1hi + off);
            ul.u = *(const uint4*)(WT1lo + off);
            b1Hi[nt][c] = uh.h;
            b1Lo[nt][c] = ul.h;
        }

    const int arow = blockIdx.x * 64 + w * 16 + lr;
    half8 aF[2];
    if (arow < Nn) {
        U4H8 v0, v1;
        v0.u = *(const uint4*)(Us + (size_t)arow * 64 + lk * 8);
        v1.u = *(const uint4*)(Us + (size_t)arow * 64 + 32 + lk * 8);
        aF[0] = v0.h;
        aF[1] = v1.h;
    } else {
        U4H8 z; z.u = make_uint4(0, 0, 0, 0);
        aF[0] = aF[1] = z.h;
    }

    f32x4 accH[4] = {}, accL[4] = {};
    #pragma unroll
    for (int nt = 0; nt < 4; nt++)
        #pragma unroll
        for (int c = 0; c < 2; c++) {
            accH[nt] = __builtin_amdgcn_mfma_f32_16x16x32_f16(
                aF[c], b1Hi[nt][c], accH[nt], 0, 0, 0);
            accL[nt] = __builtin_amdgcn_mfma_f32_16x16x32_f16(
                aF[c], b1Lo[nt][c], accL[nt], 0, 0, 0);
        }

    // M -> LDS (fp16); C/D layout: row = lk*4+j, col = nt*16+lr [m89]
    #pragma unroll
    for (int nt = 0; nt < 4; nt++) {
        const int ccol = nt * 16 + lr;
        const float bb = b1v[ccol];
        #pragma unroll
        for (int j = 0; j < 4; j++) {
            const int rloc = w * 16 + lk * 4 + j;
            const float m = fmaxf(fmaf(accL[nt][j], 1.0f / 2048.0f, accH[nt][j]) + bb, 0.f);
            Mh[rloc][ccol] = f2h(m);
        }
    }
    __syncthreads();

    // ---- stage 2: z = relu(M @ W2 + b2) ----
    half8 b2Hi[4][2], b2Lo[4][2];
    #pragma unroll
    for (int nt = 0; nt < 4; nt++)
        #pragma unroll
        for (int c = 0; c < 2; c++) {
            const int off = (nt * 16 + lr) * 64 + c * 32 + lk * 8;
            U4H8 uh, ul;
            uh.u = *(const uint4*)(WT2hi + off);
            ul.u = *(const uint4*)(WT2lo + off);
            b2Hi[nt][c] = uh.h;
            b2Lo[nt][c] = ul.h;
        }

    half8 a2F[2];
    #pragma unroll
    for (int c = 0; c < 2; c++) {
        U4H8 v;
        v.u = *(const uint4*)&Mh[w * 16 + lr][c * 32 + lk * 8];
        a2F[c] = v.h;
    }

    f32x4 acc2H[4] = {}, acc2L[4] = {};
    #pragma unroll
    for (int nt = 0; nt < 4; nt++)
        #pragma unroll
        for (int c = 0; c < 2; c++) {
            acc2H[nt] = __builtin_amdgcn_mfma_f32_16x16x32_f16(
                a2F[c], b2Hi[nt][c], acc2H[nt], 0, 0, 0);
            acc2L[nt] = __builtin_amdgcn_mfma_f32_16x16x32_f16(
                a2F[c], b2Lo[nt][c], acc2L[nt], 0, 0, 0);
        }

    float s[4], s2[4];
    #pragma unroll
    for (int nt = 0; nt < 4; nt++) {
        const int ccol = nt * 16 + lr;
        const float bb = b2v[ccol];
        s[nt] = 0.f; s2[nt] = 0.f;
        #pragma unroll
        for (int j = 0; j < 4; j++) {
            const int crow = blockIdx.x * 64 + w * 16 + lk * 4 + j;
            if (crow < Nn) {
                const float v = fmaxf(fmaf(acc2L[nt][j], 1.0f / 2048.0f, acc2H[nt][j]) + bb, 0.f);
                Zs[(size_t)crow * 64 + ccol] = f2h(v);
                s[nt] += v; s2[nt] += v * v;
            }
        }
    }

    #pragma unroll
    for (int nt = 0; nt < 4; nt++) {
        s[nt]  += __shfl_xor(s[nt], 16);  s[nt]  += __shfl_xor(s[nt], 32);
        s2[nt] += __shfl_xor(s2[nt], 16); s2[nt] += __shfl_xor(s2[nt], 32);
    }
    if (l < 16) {
        #pragma unroll
        for (int nt = 0; nt < 4; nt++) {
            red[0][w][nt][l] = s[nt];
            red[1][w][nt][l] = s2[nt];
        }
    }
    __syncthreads();
    if (t < 64) { // column = (t>>4)*16 + (t&15) = t
        float ts = 0.f, ts2 = 0.f;
        #pragma unroll
        for (int wv = 0; wv < 4; wv++) {
            ts  += red[0][wv][t >> 4][t & 15];
            ts2 += red[1][wv][t >> 4][t & 15];
        }
        // coalesced per-block partial write (no atomics)
        spart[(size_t)blockIdx.x * 128 + t] = ts;
        spart[(size_t)blockIdx.x * 128 + 64 + t] = ts2;
    }
}

// ---------------------------------------------------------------------------
// Reduce per-block stats partials (atomic-free): sp16[b][c] = partial sums.
// 16 blocks x 128 threads.
// ---------------------------------------------------------------------------
__global__ __launch_bounds__(128) void reduce_stats(
    const float* __restrict__ spart, float* __restrict__ sp16)
{
    const int t = threadIdx.x; // 0..127
    const int r0 = blockIdx.x * 98;
    const int r1 = min(r0 + 98, GG);
    float acc = 0.f;
    for (int r = r0; r < r1; r++)
        acc += spart[(size_t)r * 128 + t];
    sp16[(size_t)blockIdx.x * 128 + t] = acc;
}

// Compute scale/shift from sp16 -> sc (current) + sc5[layer].
__global__ void bn_finalize(
    const float* __restrict__ sp16, const float* __restrict__ gamma,
    const float* __restrict__ beta, float* __restrict__ sc,
    float* __restrict__ sc5, int layer)
{
    const int c = threadIdx.x; // 64 threads, 1 block
    float sum = 0.f, sum2 = 0.f;
    #pragma unroll
    for (int b = 0; b < 16; b++) {
        sum  += sp16[b * 128 + c];
        sum2 += sp16[b * 128 + 64 + c];
    }
    const float mean = sum * (1.0f / Nn);
    const float var = sum2 * (1.0f / Nn) - mean * mean;
    const float scale = gamma[layer * 64 + c] * rsqrtf(var + 1e-5f);
    const float shift = beta[layer * 64 + c] - mean * scale;
    sc[c] = scale;
    sc[64 + c] = shift;
    sc5[layer * 128 + c] = scale;
    sc5[layer * 128 + 64 + c] = shift;
}

// ---------------------------------------------------------------------------
// Per-graph raw-z sums from spart (full blocks) + Zs (boundary rows).
// One block (64 threads) per graph. Writes poolZ[g][c] (no atomics).
// ---------------------------------------------------------------------------
__global__ __launch_bounds__(64) void reduce_pool(
    const float* __restrict__ spart, const ushort* __restrict__ zs,
    const int* __restrict__ batch, float* __restrict__ poolZ)
{
    const int g = blockIdx.x;
    const int c = threadIdx.x; // 0..63
    const int lo = lower_bound_i(batch, Nn, g);
    const int hi = lower_bound_i(batch, Nn, g + 1);
    const int bs = (lo + 63) >> 6;  // first full block
    const int be = hi >> 6;         // one past last full block
    float acc = 0.f;
    if (bs <= be) {
        for (int b = bs; b < be; b++)
            acc += spart[(size_t)b * 128 + c];
        for (int r = lo; r < bs * 64; r++)
            acc += h2f(zs[(size_t)r * 64 + c]);
        for (int r = be * 64; r < hi; r++)
            acc += h2f(zs[(size_t)r * 64 + c]);
    } else {
        for (int r = lo; r < hi; r++)
            acc += h2f(zs[(size_t)r * 64 + c]);
    }
    poolZ[g * 64 + c] = acc;
}

// ---------------------------------------------------------------------------
// Bucketed CSR build.
// ---------------------------------------------------------------------------
__global__ __launch_bounds__(256) void bin_edges(
    const int* __restrict__ ei, int* __restrict__ gCursor,
    uint2* __restrict__ binned)
{
    __shared__ int hist[NB];
    __shared__ int base[NB];
    __shared__ int cur[NB];
    const int t = threadIdx.x;
    const int e0 = blockIdx.x * CHUNK;
    const int eEnd = min(e0 + CHUNK, Ee);
    if (t < NB) hist[t] = 0;
    __syncthreads();
    for (int e = e0 + t; e < eEnd; e += 256)
        atomicAdd(&hist[ei[Ee + e] >> 10], 1);
    __syncthreads();
    if (t < NB) {
        base[t] = atomicAdd(&gCursor[t], hist[t]);
        cur[t] = 0;
    }
    __syncthreads();
    for (int e = e0 + t; e < eEnd; e += 256) {
        const int s = ei[e];
        const int d = ei[Ee + e];
        const int b = d >> 10;
        const int pos = atomicAdd(&cur[b], 1);
        binned[(size_t)base[b] + pos] = make_uint2((uint)d, (uint)s);
    }
}

__global__ __launch_bounds__(128) void scan_buckets(
    const int* __restrict__ gCursor, int* __restrict__ bucketBase)
{
    __shared__ int sh[128];
    const int t = threadIdx.x;
    const int c = (t < NB) ? gCursor[t] - t * BCAP : 0;
    sh[t] = c;
    __syncthreads();
    for (int off = 1; off < 128; off <<= 1) {
        const int u = (t >= off) ? sh[t - off] : 0;
        __syncthreads();
        sh[t] += u;
        __syncthreads();
    }
    bucketBase[t] = sh[t] - c; // exclusive
}

__global__ __launch_bounds__(256) void build_csr(
    const uint2* __restrict__ binned, const int* __restrict__ gCursor,
    const int* __restrict__ bucketBase, int* __restrict__ rowptr,
    int* __restrict__ colidx)
{
    __shared__ int degS[1024];
    __shared__ int sh[256];
    __shared__ int colStage[BCAP];
    const int b = blockIdx.x;
    const int t = threadIdx.x;
    const int cnt = gCursor[b] - b * BCAP;
    const int base = bucketBase[b];
    const uint2* src = binned + (size_t)b * BCAP;

    for (int i = t; i < 1024; i += 256) degS[i] = 0;
    __syncthreads();
    for (int i = t; i < cnt; i += 256)
        atomicAdd(&degS[src[i].x & 1023], 1);
    __syncthreads();

    const int b4 = t * 4;
    const int v0 = degS[b4], v1 = degS[b4 + 1], v2 = degS[b4 + 2], v3 = degS[b4 + 3];
    const int sSum = v0 + v1 + v2 + v3;
    sh[t] = sSum;
    __syncthreads();
    for (int off = 1; off < 256; off <<= 1) {
        const int u = (t >= off) ? sh[t - off] : 0;
        __syncthreads();
        sh[t] += u;
        __syncthreads();
    }
    const int excl = sh[t] - sSum;
    const int p0 = excl, p1 = excl + v0, p2 = excl + v0 + v1, p3 = excl + v0 + v1 + v2;

    const int grow = b * 1024 + b4;
    if (grow + 3 <= Nn) {
        *(int4*)(rowptr + grow) = make_int4(base + p0, base + p1, base + p2, base + p3);
    } else {
        if (grow + 0 <= Nn) rowptr[grow + 0] = base + p0;
        if (grow + 1 <= Nn) rowptr[grow + 1] = base + p1;
        if (grow + 2 <= Nn) rowptr[grow + 2] = base + p2;
        if (grow + 3 <= Nn) rowptr[grow + 3] = base + p3;
    }

    degS[b4] = p0; degS[b4 + 1] = p1; degS[b4 + 2] = p2; degS[b4 + 3] = p3;
    __syncthreads();
    for (int i = t; i < cnt; i += 256) {
        const uint2 p = src[i];
        const int pos = atomicAdd(&degS[p.x & 1023], 1);
        colStage[pos] = (int)p.y;
    }
    __syncthreads();
    for (int i = t; i < cnt; i += 256) colidx[base + i] = colStage[i];
}

// ---------------------------------------------------------------------------
// Gather + deferred BN: u[r] = scale ∘ (z[r] + Σ_{j∈N(r)} z[j]) + (1+deg)*shift.
// 4-way unrolled independent gathers (proven round-14 config).
// z fp16 in, u fp16 out, affine in f32. 8 lanes per row, 32 rows per block.
// ---------------------------------------------------------------------------
__global__ __launch_bounds__(256) void gather_bn(
    const int* __restrict__ rowptr, const int* __restrict__ col,
    const ushort* __restrict__ zs, const float* __restrict__ sc,
    ushort* __restrict__ us)
{
    __shared__ float scS[128];
    const int t = threadIdx.x;
    if (t < 128) scS[t] = sc[t];
    __syncthreads();

    const int r = blockIdx.x * 32 + (t >> 3);
    const int q = t & 7;
    const int beg = rowptr[r], end = rowptr[r + 1];
    float a[8];
    {
        const uint4 v = *(const uint4*)(zs + (size_t)r * 64 + q * 8); // self
        a[0] = h2f_lo(v.x); a[1] = h2f_hi(v.x);
        a[2] = h2f_lo(v.y); a[3] = h2f_hi(v.y);
        a[4] = h2f_lo(v.z); a[5] = h2f_hi(v.z);
        a[6] = h2f_lo(v.w); a[7] = h2f_hi(v.w);
    }
    int j = beg;
    const int end4 = beg + ((end - beg) & ~3);
    for (; j < end4; j += 4) {
        const int s0 = col[j], s1 = col[j + 1], s2 = col[j + 2], s3 = col[j + 3];
        const uint4 v0 = *(const uint4*)(zs + (size_t)s0 * 64 + q * 8);
        const uint4 v1 = *(const uint4*)(zs + (size_t)s1 * 64 + q * 8);
        const uint4 v2 = *(const uint4*)(zs + (size_t)s2 * 64 + q * 8);
        const uint4 v3 = *(const uint4*)(zs + (size_t)s3 * 64 + q * 8);
        a[0] += h2f_lo(v0.x) + h2f_lo(v1.x) + h2f_lo(v2.x) + h2f_lo(v3.x);
        a[1] += h2f_hi(v0.x) + h2f_hi(v1.x) + h2f_hi(v2.x) + h2f_hi(v3.x);
        a[2] += h2f_lo(v0.y) + h2f_lo(v1.y) + h2f_lo(v2.y) + h2f_lo(v3.y);
        a[3] += h2f_hi(v0.y) + h2f_hi(v1.y) + h2f_hi(v2.y) + h2f_hi(v3.y);
        a[4] += h2f_lo(v0.z) + h2f_lo(v1.z) + h2f_lo(v2.z) + h2f_lo(v3.z);
        a[5] += h2f_hi(v0.z) + h2f_hi(v1.z) + h2f_hi(v2.z) + h2f_hi(v3.z);
        a[6] += h2f_lo(v0.w) + h2f_lo(v1.w) + h2f_lo(v2.w) + h2f_lo(v3.w);
        a[7] += h2f_hi(v0.w) + h2f_hi(v1.w) + h2f_hi(v2.w) + h2f_hi(v3.w);
    }
    for (; j < end; j++) {
        const int s = col[j];
        const uint4 v = *(const uint4*)(zs + (size_t)s * 64 + q * 8);
        a[0] += h2f_lo(v.x); a[1] += h2f_hi(v.x);
        a[2] += h2f_lo(v.y); a[3] += h2f_hi(v.y);
        a[4] += h2f_lo(v.z); a[5] += h2f_hi(v.z);
        a[6] += h2f_lo(v.w); a[7] += h2f_hi(v.w);
    }
    const float dgf = (float)(end - beg + 1);
    float o[8];
    #pragma unroll
    for (int i = 0; i < 8; i++)
        o[i] = fmaf(scS[q * 8 + i], a[i], dgf * scS[64 + q * 8 + i]);
    uint4 p;
    p.x = pack2h(o[0], o[1]); p.y = pack2h(o[2], o[3]);
    p.z = pack2h(o[4], o[5]); p.w = pack2h(o[6], o[7]);
    *(uint4*)(us + (size_t)r * 64 + q * 8) = p;
}

// ---------------------------------------------------------------------------
// Final pooled transform across all layers:
// pooled[g][l*64+c] = sc5[l][c]*poolZ[l][g][c] + cnt[g]*sc5[l][64+c]
// ---------------------------------------------------------------------------
__global__ __launch_bounds__(256) void final_pool(
    const float* __restrict__ sc5, const float* __restrict__ poolZ,
    const int* __restrict__ cnt, float* __restrict__ pooled)
{
    const int idx = blockIdx.x * 256 + threadIdx.x; // 40960
    const int c = idx & 63;
    const int g = (idx >> 6) & 127;
    const int l = idx >> 13;
    pooled[g * PDim + l * 64 + c] =
        sc5[l * 128 + c] * poolZ[(size_t)l * Gg * 64 + g * 64 + c]
        + (float)cnt[g] * sc5[l * 128 + 64 + c];
}

// ---------------------------------------------------------------------------
// Proj head GEMM: (128,320)@(320,320)+b (f32, small).
// ---------------------------------------------------------------------------
template<bool RELU>
__global__ __launch_bounds__(256) void proj(
    const float* __restrict__ X, const float* __restrict__ W,
    const float* __restrict__ bias, float* __restrict__ Y)
{
    const int idx = blockIdx.x * 256 + threadIdx.x; // 40960 exact
    const int r = idx / PDim;
    const int c = idx - r * PDim;
    float acc = bias[c];
    #pragma unroll 8
    for (int k = 0; k < PDim; k++)
        acc = fmaf(X[r * PDim + k], W[k * PDim + c], acc);
    if constexpr (RELU) acc = fmaxf(acc, 0.f);
    Y[idx] = acc;
}

// ---------------------------------------------------------------------------
// Row-wise l2 normalize.
// ---------------------------------------------------------------------------
__global__ __launch_bounds__(64) void l2norm_rows(
    const float* __restrict__ X, float* __restrict__ out)
{
    const int r = blockIdx.x;
    const int l = threadIdx.x;
    float v[5];
    float s = 0.f;
    #pragma unroll
    for (int i = 0; i < 5; i++) {
        v[i] = X[r * PDim + i * 64 + l];
        s += v[i] * v[i];
    }
    #pragma unroll
    for (int off = 32; off > 0; off >>= 1) s += __shfl_down(s, off);
    s = __shfl(s, 0);
    const float d = fmaxf(sqrtf(s), 1e-12f);
    #pragma unroll
    for (int i = 0; i < 5; i++)
        out[r * PDim + i * 64 + l] = v[i] / d;
}

// ---------------------------------------------------------------------------
extern "C" void kernel_launch(void* const* d_in, const int* in_sizes, int n_in,
                              void* d_out, int out_size, void* d_ws, size_t ws_size,
                              hipStream_t stream)
{
    const float* x     = (const float*)d_in[0];
    const int*   ei    = (const int*)d_in[1];
    const int*   batch = (const int*)d_in[2];
    const float* Ws    = (const float*)d_in[3];
    const float* bs    = (const float*)d_in[4];
    const float* W1    = (const float*)d_in[5];
    const float* b1    = (const float*)d_in[6];
    const float* W2    = (const float*)d_in[7];
    const float* b2    = (const float*)d_in[8];
    const float* gamma = (const float*)d_in[9];
    const float* beta  = (const float*)d_in[10];
    const float* Wp1   = (const float*)d_in[11];
    const float* bp1   = (const float*)d_in[12];
    const float* Wp2   = (const float*)d_in[13];
    const float* bp2   = (const float*)d_in[14];
    float* out = (float*)d_out;

    // workspace
    ushort* Us = (ushort*)d_ws;                   // u  fp16 (N*64)  12.8MB
    ushort* Zs = Us + (size_t)Nn * 64;            // z  fp16         12.8MB
    ushort* WThi = Zs + (size_t)Nn * 64;          // 11*4096 fp16
    ushort* WTlo = WThi + 11 * 4096;
    float* pooled = (float*)(WTlo + 11 * 4096);   // (G,320)
    float* ytmp   = pooled + (size_t)Gg * PDim;
    float* ypro   = ytmp + (size_t)Gg * PDim;
    float* sp16   = ypro + (size_t)Gg * PDim;     // 16*128
    float* sc     = sp16 + 16 * 128;              // 128
    float* sc5    = sc + 128;                     // 5*128
    float* poolZ  = sc5 + 5 * 128;                // 5*G*64
    float* spart  = poolZ + 5 * Gg * 64;          // GG*128 (800KB)
    int* cnt    = (int*)(spart + (size_t)GG * 128); // 128
    int* rowptr = cnt + 128;                      // Nn+1
    int* colidx = rowptr + Nn + 1;                // Ee
    int* gCursor = colidx + Ee;                   // 128 (NB used)
    int* bucketBase = gCursor + 128;              // 128
    size_t woff = (size_t)((bucketBase + 128) - (int*)d_ws);
    woff = (woff + 1) & ~(size_t)1;
    uint2* binned = (uint2*)((int*)d_ws + woff);  // NB*BCAP*8B = 12.6MB

    init_csr<<<1, 128, 0, stream>>>(batch, gCursor, cnt, sc);
    conv_weights<<<11, 256, 0, stream>>>(Ws, W1, W2, WThi, WTlo);

    // bucketed CSR build
    bin_edges<<<NBLK_A, 256, 0, stream>>>(ei, gCursor, binned);
    scan_buckets<<<1, 128, 0, stream>>>(gCursor, bucketBase);
    build_csr<<<NB, 256, 0, stream>>>(binned, gCursor, bucketBase, rowptr, colidx);

    // encoder: Zs = fp16(x @ Ws + bs)   (raw z_0; BN identity in sc)
    gemm_enc<<<GG, 256, 0, stream>>>(x, WThi, WTlo, bs, Zs);

    for (int l = 0; l < Ll; l++) {
        // u = BN_{l-1} applied to inclusive sum of raw z (affine distributes)
        gather_bn<<<Nn / 32, 256, 0, stream>>>(rowptr, colidx, Zs, sc, Us);
        fused_mlp<<<GG, 256, 0, stream>>>(
            Us,
            WThi + (size_t)(1 + l) * 4096, WTlo + (size_t)(1 + l) * 4096,
            b1 + (size_t)l * 64,
            WThi + (size_t)(6 + l) * 4096, WTlo + (size_t)(6 + l) * 4096,
            b2 + (size_t)l * 64,
            Zs, spart);
        reduce_stats<<<16, 128, 0, stream>>>(spart, sp16);
        bn_finalize<<<1, 64, 0, stream>>>(sp16, gamma, beta, sc, sc5, l);
        reduce_pool<<<Gg, 64, 0, stream>>>(spart, Zs, batch,
                                           poolZ + (size_t)l * Gg * 64);
    }

    final_pool<<<160, 256, 0, stream>>>(sc5, poolZ, cnt, pooled);

    // proj head (f32)
    proj<true><<<160, 256, 0, stream>>>(pooled, Wp1, bp1, ytmp);
    proj<false><<<160, 256, 0, stream>>>(ytmp, Wp2, bp2, ypro);

    l2norm_rows<<<Gg, 64, 0, stream>>>(ypro, out);               // out0
    l2norm_rows<<<Gg, 64, 0, stream>>>(pooled, out + Gg * PDim); // out1
}

// Round 17
// 569.108 us; speedup vs baseline: 1.3603x; 1.3158x over previous
//
#include <hip/hip_runtime.h>
#include <hip/hip_bf16.h>
#include <hip/hip_fp16.h>

constexpr int Nn = 100000;
constexpr int Ee = 1200000;
constexpr int Ll = 5;
constexpr int Gg = 128;
constexpr int PDim = 320; // L*D
constexpr int GG = (Nn + 63) / 64; // 1563 gemm blocks

// bucketed CSR build params
constexpr int NB    = 98;     // buckets of 1024 rows (dst >> 10)
constexpr int BCAP  = 16384;  // per-bucket edge capacity
constexpr int CHUNK = 4096;   // edges per bin_edges block
constexpr int NBLK_A = (Ee + CHUNK - 1) / CHUNK; // 293

typedef float f32x4 __attribute__((ext_vector_type(4)));
typedef _Float16 half8 __attribute__((ext_vector_type(8)));

union U4H8 { uint4 u; half8 h; };

__device__ inline ushort f2h(float f) {
    const __half h = __float2half(f);
    return *(const ushort*)&h;
}
__device__ inline uint pack2h(float lo, float hi) {
    return (uint)f2h(lo) | ((uint)f2h(hi) << 16);
}
__device__ inline float h2f_lo(uint u) {
    const ushort s = (ushort)(u & 0xffffu);
    return __half2float(*(const __half*)&s);
}
__device__ inline float h2f_hi(uint u) {
    const ushort s = (ushort)(u >> 16);
    return __half2float(*(const __half*)&s);
}

__device__ inline int lower_bound_i(const int* __restrict__ a, int n, int v)
{
    int lo = 0, hi = n;
    while (lo < hi) {
        const int m = (lo + hi) >> 1;
        if (a[m] < v) lo = m + 1; else hi = m;
    }
    return lo;
}

// ---------------------------------------------------------------------------
// init: gCursor for buckets, per-graph node counts, identity BN sc.
// ---------------------------------------------------------------------------
__global__ void init_csr(const int* __restrict__ batch, int* __restrict__ gCursor,
                         int* __restrict__ cnt, float* __restrict__ sc)
{
    const int t = threadIdx.x; // 128
    if (t < NB) gCursor[t] = t * BCAP;
    {
        const int lo = lower_bound_i(batch, Nn, t);
        const int hi = lower_bound_i(batch, Nn, t + 1);
        cnt[t] = hi - lo;
    }
    if (t < 64) { sc[t] = 1.f; sc[64 + t] = 0.f; }
}

// ---------------------------------------------------------------------------
// Weight conversion: 11 64x64 f32 matrices -> TRANSPOSED fp16 hi + fp16
// (residual*2048) lo. 22-bit effective weight precision.
// Block m: 0=Ws, 1..5=W1[m-1], 6..10=W2[m-6].
// ---------------------------------------------------------------------------
__global__ __launch_bounds__(256) void conv_weights(
    const float* __restrict__ Ws, const float* __restrict__ W1,
    const float* __restrict__ W2, ushort* __restrict__ WThi,
    ushort* __restrict__ WTlo)
{
    const int m = blockIdx.x;
    const float* src = (m == 0) ? Ws
                     : (m <= 5) ? W1 + (size_t)(m - 1) * 4096
                                : W2 + (size_t)(m - 6) * 4096;
    ushort* dh = WThi + (size_t)m * 4096;
    ushort* dl = WTlo + (size_t)m * 4096;
    const int t = threadIdx.x;
    const int col = t & 63;
    const int k0 = (t >> 6) * 16;
    #pragma unroll
    for (int i = 0; i < 16; i++) {
        const int k = k0 + i;
        const float w = src[k * 64 + col];
        const ushort h = f2h(w);
        dh[col * 64 + k] = h;
        const float resid = (w - h2f_lo((uint)h)) * 2048.0f;
        dl[col * 64 + k] = f2h(resid);
    }
}

// ---------------------------------------------------------------------------
// Encoder GEMM (fp16 MFMA): Zs = fp16(x @ Ws + bs).
// ---------------------------------------------------------------------------
__global__ __launch_bounds__(256) void gemm_enc(
    const float* __restrict__ A1,
    const ushort* __restrict__ WThi, const ushort* __restrict__ WTlo,
    const float* __restrict__ bias, ushort* __restrict__ Ys)
{
    const int t = threadIdx.x;
    const int w = t >> 6;
    const int l = t & 63;
    const int lr = l & 15;
    const int lk = l >> 4;

    half8 bHi[4][2], bLo[4][2];
    #pragma unroll
    for (int nt = 0; nt < 4; nt++)
        #pragma unroll
        for (int c = 0; c < 2; c++) {
            const int off = (nt * 16 + lr) * 64 + c * 32 + lk * 8;
            U4H8 uh, ul;
            uh.u = *(const uint4*)(WThi + off);
            ul.u = *(const uint4*)(WTlo + off);
            bHi[nt][c] = uh.h;
            bLo[nt][c] = ul.h;
        }

    const int arow = blockIdx.x * 64 + w * 16 + lr;
    half8 aHi[2], aLo[2];
    if (arow < Nn) {
        #pragma unroll
        for (int c = 0; c < 2; c++) {
            const float* p1 = A1 + (size_t)arow * 64 + c * 32 + lk * 8;
            U4H8 rh, rl;
            #pragma unroll
            for (int i = 0; i < 8; i++) {
                const float xv = p1[i];
                const _Float16 xh = (_Float16)xv;
                rh.h[i] = xh;
                rl.h[i] = (_Float16)((xv - (float)xh) * 2048.0f);
            }
            aHi[c] = rh.h;
            aLo[c] = rl.h;
        }
    } else {
        U4H8 z; z.u = make_uint4(0, 0, 0, 0);
        aHi[0] = aHi[1] = z.h;
        aLo[0] = aLo[1] = z.h;
    }

    f32x4 accH[4] = {}, accL[4] = {};
    #pragma unroll
    for (int nt = 0; nt < 4; nt++)
        #pragma unroll
        for (int c = 0; c < 2; c++) {
            accH[nt] = __builtin_amdgcn_mfma_f32_16x16x32_f16(
                aHi[c], bHi[nt][c], accH[nt], 0, 0, 0);
            accL[nt] = __builtin_amdgcn_mfma_f32_16x16x32_f16(
                aHi[c], bLo[nt][c], accL[nt], 0, 0, 0);
            accL[nt] = __builtin_amdgcn_mfma_f32_16x16x32_f16(
                aLo[c], bHi[nt][c], accL[nt], 0, 0, 0);
        }

    #pragma unroll
    for (int nt = 0; nt < 4; nt++) {
        const int ccol = nt * 16 + lr;
        const float bb = bias[ccol];
        #pragma unroll
        for (int j = 0; j < 4; j++) {
            const int crow = blockIdx.x * 64 + w * 16 + lk * 4 + j;
            if (crow < Nn)
                Ys[(size_t)crow * 64 + ccol] =
                    f2h(fmaf(accL[nt][j], 1.0f / 2048.0f, accH[nt][j]) + bb);
        }
    }
}

// ---------------------------------------------------------------------------
// Fused GIN MLP (fp16 MFMA): Zs = fp16(relu(relu(u@W1+b1)@W2+b2)).
// Per-column BN stats -> per-block PARTIAL writes (spart[blk][128], no
// same-address atomics; reduced by reduce_stats). M in LDS fp16 [64][72].
// ---------------------------------------------------------------------------
__global__ __launch_bounds__(256) void fused_mlp(
    const ushort* __restrict__ Us,
    const ushort* __restrict__ WT1hi, const ushort* __restrict__ WT1lo,
    const float* __restrict__ b1v,
    const ushort* __restrict__ WT2hi, const ushort* __restrict__ WT2lo,
    const float* __restrict__ b2v,
    ushort* __restrict__ Zs, float* __restrict__ spart)
{
    const int t = threadIdx.x;
    const int w = t >> 6;
    const int l = t & 63;
    const int lr = l & 15;   // A-row / B-col within 16-tile
    const int lk = l >> 4;   // k-group (8 elems each)

    __shared__ ushort Mh[64][72];
    __shared__ float red[2][4][4][16];

    // ---- stage 1: M = relu(u @ W1 + b1) ----
    half8 b1Hi[4][2], b1Lo[4][2];
    #pragma unroll
    for (int nt = 0; nt < 4; nt++)
        #pragma unroll
        for (int c = 0; c < 2; c++) {
            const int off = (nt * 16 + lr) * 64 + c * 32 + lk * 8;
            U4H8 uh, ul;
            uh.u = *(const uint4*)(WT1hi + off);
            ul.u = *(const uint4*)(WT1lo + off);
            b1Hi[nt][c] = uh.h;
            b1Lo[nt][c] = ul.h;
        }

    const int arow = blockIdx.x * 64 + w * 16 + lr;
    half8 aF[2];
    if (arow < Nn) {
        U4H8 v0, v1;
        v0.u = *(const uint4*)(Us + (size_t)arow * 64 + lk * 8);
        v1.u = *(const uint4*)(Us + (size_t)arow * 64 + 32 + lk * 8);
        aF[0] = v0.h;
        aF[1] = v1.h;
    } else {
        U4H8 z; z.u = make_uint4(0, 0, 0, 0);
        aF[0] = aF[1] = z.h;
    }

    f32x4 accH[4] = {}, accL[4] = {};
    #pragma unroll
    for (int nt = 0; nt < 4; nt++)
        #pragma unroll
        for (int c = 0; c < 2; c++) {
            accH[nt] = __builtin_amdgcn_mfma_f32_16x16x32_f16(
                aF[c], b1Hi[nt][c], accH[nt], 0, 0, 0);
            accL[nt] = __builtin_amdgcn_mfma_f32_16x16x32_f16(
                aF[c], b1Lo[nt][c], accL[nt], 0, 0, 0);
        }

    // M -> LDS (fp16); C/D layout: row = lk*4+j, col = nt*16+lr [m89]
    #pragma unroll
    for (int nt = 0; nt < 4; nt++) {
        const int ccol = nt * 16 + lr;
        const float bb = b1v[ccol];
        #pragma unroll
        for (int j = 0; j < 4; j++) {
            const int rloc = w * 16 + lk * 4 + j;
            const float m = fmaxf(fmaf(accL[nt][j], 1.0f / 2048.0f, accH[nt][j]) + bb, 0.f);
            Mh[rloc][ccol] = f2h(m);
        }
    }
    __syncthreads();

    // ---- stage 2: z = relu(M @ W2 + b2) ----
    half8 b2Hi[4][2], b2Lo[4][2];
    #pragma unroll
    for (int nt = 0; nt < 4; nt++)
        #pragma unroll
        for (int c = 0; c < 2; c++) {
            const int off = (nt * 16 + lr) * 64 + c * 32 + lk * 8;
            U4H8 uh, ul;
            uh.u = *(const uint4*)(WT2hi + off);
            ul.u = *(const uint4*)(WT2lo + off);
            b2Hi[nt][c] = uh.h;
            b2Lo[nt][c] = ul.h;
        }

    half8 a2F[2];
    #pragma unroll
    for (int c = 0; c < 2; c++) {
        U4H8 v;
        v.u = *(const uint4*)&Mh[w * 16 + lr][c * 32 + lk * 8];
        a2F[c] = v.h;
    }

    f32x4 acc2H[4] = {}, acc2L[4] = {};
    #pragma unroll
    for (int nt = 0; nt < 4; nt++)
        #pragma unroll
        for (int c = 0; c < 2; c++) {
            acc2H[nt] = __builtin_amdgcn_mfma_f32_16x16x32_f16(
                a2F[c], b2Hi[nt][c], acc2H[nt], 0, 0, 0);
            acc2L[nt] = __builtin_amdgcn_mfma_f32_16x16x32_f16(
                a2F[c], b2Lo[nt][c], acc2L[nt], 0, 0, 0);
        }

    float s[4], s2[4];
    #pragma unroll
    for (int nt = 0; nt < 4; nt++) {
        const int ccol = nt * 16 + lr;
        const float bb = b2v[ccol];
        s[nt] = 0.f; s2[nt] = 0.f;
        #pragma unroll
        for (int j = 0; j < 4; j++) {
            const int crow = blockIdx.x * 64 + w * 16 + lk * 4 + j;
            if (crow < Nn) {
                const float v = fmaxf(fmaf(acc2L[nt][j], 1.0f / 2048.0f, acc2H[nt][j]) + bb, 0.f);
                Zs[(size_t)crow * 64 + ccol] = f2h(v);
                s[nt] += v; s2[nt] += v * v;
            }
        }
    }

    #pragma unroll
    for (int nt = 0; nt < 4; nt++) {
        s[nt]  += __shfl_xor(s[nt], 16);  s[nt]  += __shfl_xor(s[nt], 32);
        s2[nt] += __shfl_xor(s2[nt], 16); s2[nt] += __shfl_xor(s2[nt], 32);
    }
    if (l < 16) {
        #pragma unroll
        for (int nt = 0; nt < 4; nt++) {
            red[0][w][nt][l] = s[nt];
            red[1][w][nt][l] = s2[nt];
        }
    }
    __syncthreads();
    if (t < 64) { // column = (t>>4)*16 + (t&15) = t
        float ts = 0.f, ts2 = 0.f;
        #pragma unroll
        for (int wv = 0; wv < 4; wv++) {
            ts  += red[0][wv][t >> 4][t & 15];
            ts2 += red[1][wv][t >> 4][t & 15];
        }
        // coalesced per-block partial write (no atomics)
        spart[(size_t)blockIdx.x * 128 + t] = ts;
        spart[(size_t)blockIdx.x * 128 + 64 + t] = ts2;
    }
}

// ---------------------------------------------------------------------------
// Reduce per-block stats partials: stats[c] += sum_b spart[b][c].
// 16 blocks x 256 threads; coalesced reads; 16-way atomic contention only.
// ---------------------------------------------------------------------------
__global__ __launch_bounds__(256) void reduce_stats(
    const float* __restrict__ spart, float* __restrict__ stats)
{
    const int t = threadIdx.x;
    const int col = t & 127;
    const int half = t >> 7; // 0 or 1
    const int r0 = blockIdx.x * 98;
    const int r1 = min(r0 + 98, GG);
    float acc = 0.f;
    for (int r = r0 + half; r < r1; r += 2)
        acc += spart[(size_t)r * 128 + col];
    atomicAdd(&stats[col], acc);
}

// ---------------------------------------------------------------------------
// Bucketed CSR build.
// ---------------------------------------------------------------------------
__global__ __launch_bounds__(256) void bin_edges(
    const int* __restrict__ ei, int* __restrict__ gCursor,
    uint2* __restrict__ binned)
{
    __shared__ int hist[NB];
    __shared__ int base[NB];
    __shared__ int cur[NB];
    const int t = threadIdx.x;
    const int e0 = blockIdx.x * CHUNK;
    const int eEnd = min(e0 + CHUNK, Ee);
    if (t < NB) hist[t] = 0;
    __syncthreads();
    for (int e = e0 + t; e < eEnd; e += 256)
        atomicAdd(&hist[ei[Ee + e] >> 10], 1);
    __syncthreads();
    if (t < NB) {
        base[t] = atomicAdd(&gCursor[t], hist[t]);
        cur[t] = 0;
    }
    __syncthreads();
    for (int e = e0 + t; e < eEnd; e += 256) {
        const int s = ei[e];
        const int d = ei[Ee + e];
        const int b = d >> 10;
        const int pos = atomicAdd(&cur[b], 1);
        binned[(size_t)base[b] + pos] = make_uint2((uint)d, (uint)s);
    }
}

__global__ __launch_bounds__(128) void scan_buckets(
    const int* __restrict__ gCursor, int* __restrict__ bucketBase)
{
    __shared__ int sh[128];
    const int t = threadIdx.x;
    const int c = (t < NB) ? gCursor[t] - t * BCAP : 0;
    sh[t] = c;
    __syncthreads();
    for (int off = 1; off < 128; off <<= 1) {
        const int u = (t >= off) ? sh[t - off] : 0;
        __syncthreads();
        sh[t] += u;
        __syncthreads();
    }
    bucketBase[t] = sh[t] - c; // exclusive
}

__global__ __launch_bounds__(256) void build_csr(
    const uint2* __restrict__ binned, const int* __restrict__ gCursor,
    const int* __restrict__ bucketBase, int* __restrict__ rowptr,
    int* __restrict__ colidx)
{
    __shared__ int degS[1024];
    __shared__ int sh[256];
    __shared__ int colStage[BCAP];
    const int b = blockIdx.x;
    const int t = threadIdx.x;
    const int cnt = gCursor[b] - b * BCAP;
    const int base = bucketBase[b];
    const uint2* src = binned + (size_t)b * BCAP;

    for (int i = t; i < 1024; i += 256) degS[i] = 0;
    __syncthreads();
    for (int i = t; i < cnt; i += 256)
        atomicAdd(&degS[src[i].x & 1023], 1);
    __syncthreads();

    const int b4 = t * 4;
    const int v0 = degS[b4], v1 = degS[b4 + 1], v2 = degS[b4 + 2], v3 = degS[b4 + 3];
    const int sSum = v0 + v1 + v2 + v3;
    sh[t] = sSum;
    __syncthreads();
    for (int off = 1; off < 256; off <<= 1) {
        const int u = (t >= off) ? sh[t - off] : 0;
        __syncthreads();
        sh[t] += u;
        __syncthreads();
    }
    const int excl = sh[t] - sSum;
    const int p0 = excl, p1 = excl + v0, p2 = excl + v0 + v1, p3 = excl + v0 + v1 + v2;

    const int grow = b * 1024 + b4;
    if (grow + 3 <= Nn) {
        *(int4*)(rowptr + grow) = make_int4(base + p0, base + p1, base + p2, base + p3);
    } else {
        if (grow + 0 <= Nn) rowptr[grow + 0] = base + p0;
        if (grow + 1 <= Nn) rowptr[grow + 1] = base + p1;
        if (grow + 2 <= Nn) rowptr[grow + 2] = base + p2;
        if (grow + 3 <= Nn) rowptr[grow + 3] = base + p3;
    }

    degS[b4] = p0; degS[b4 + 1] = p1; degS[b4 + 2] = p2; degS[b4 + 3] = p3;
    __syncthreads();
    for (int i = t; i < cnt; i += 256) {
        const uint2 p = src[i];
        const int pos = atomicAdd(&degS[p.x & 1023], 1);
        colStage[pos] = (int)p.y;
    }
    __syncthreads();
    for (int i = t; i < cnt; i += 256) colidx[base + i] = colStage[i];
}

// ---------------------------------------------------------------------------
// Gather + deferred BN: u[r] = scale ∘ (z[r] + Σ_{j∈N(r)} z[j]) + (1+deg)*shift.
// 4-way unrolled independent gathers for memory-level parallelism.
// z fp16 in, u fp16 out, affine in f32. 8 lanes per row, 32 rows per block.
// ---------------------------------------------------------------------------
__global__ __launch_bounds__(256) void gather_bn(
    const int* __restrict__ rowptr, const int* __restrict__ col,
    const ushort* __restrict__ zs, const float* __restrict__ sc,
    ushort* __restrict__ us)
{
    __shared__ float scS[128];
    const int t = threadIdx.x;
    if (t < 128) scS[t] = sc[t];
    __syncthreads();

    const int r = blockIdx.x * 32 + (t >> 3);
    const int q = t & 7;
    const int beg = rowptr[r], end = rowptr[r + 1];
    float a[8];
    {
        const uint4 v = *(const uint4*)(zs + (size_t)r * 64 + q * 8); // self
        a[0] = h2f_lo(v.x); a[1] = h2f_hi(v.x);
        a[2] = h2f_lo(v.y); a[3] = h2f_hi(v.y);
        a[4] = h2f_lo(v.z); a[5] = h2f_hi(v.z);
        a[6] = h2f_lo(v.w); a[7] = h2f_hi(v.w);
    }
    int j = beg;
    const int end4 = beg + ((end - beg) & ~3);
    for (; j < end4; j += 4) {
        const int s0 = col[j], s1 = col[j + 1], s2 = col[j + 2], s3 = col[j + 3];
        const uint4 v0 = *(const uint4*)(zs + (size_t)s0 * 64 + q * 8);
        const uint4 v1 = *(const uint4*)(zs + (size_t)s1 * 64 + q * 8);
        const uint4 v2 = *(const uint4*)(zs + (size_t)s2 * 64 + q * 8);
        const uint4 v3 = *(const uint4*)(zs + (size_t)s3 * 64 + q * 8);
        a[0] += h2f_lo(v0.x) + h2f_lo(v1.x) + h2f_lo(v2.x) + h2f_lo(v3.x);
        a[1] += h2f_hi(v0.x) + h2f_hi(v1.x) + h2f_hi(v2.x) + h2f_hi(v3.x);
        a[2] += h2f_lo(v0.y) + h2f_lo(v1.y) + h2f_lo(v2.y) + h2f_lo(v3.y);
        a[3] += h2f_hi(v0.y) + h2f_hi(v1.y) + h2f_hi(v2.y) + h2f_hi(v3.y);
        a[4] += h2f_lo(v0.z) + h2f_lo(v1.z) + h2f_lo(v2.z) + h2f_lo(v3.z);
        a[5] += h2f_hi(v0.z) + h2f_hi(v1.z) + h2f_hi(v2.z) + h2f_hi(v3.z);
        a[6] += h2f_lo(v0.w) + h2f_lo(v1.w) + h2f_lo(v2.w) + h2f_lo(v3.w);
        a[7] += h2f_hi(v0.w) + h2f_hi(v1.w) + h2f_hi(v2.w) + h2f_hi(v3.w);
    }
    for (; j < end; j++) {
        const int s = col[j];
        const uint4 v = *(const uint4*)(zs + (size_t)s * 64 + q * 8);
        a[0] += h2f_lo(v.x); a[1] += h2f_hi(v.x);
        a[2] += h2f_lo(v.y); a[3] += h2f_hi(v.y);
        a[4] += h2f_lo(v.z); a[5] += h2f_hi(v.z);
        a[6] += h2f_lo(v.w); a[7] += h2f_hi(v.w);
    }
    const float dgf = (float)(end - beg + 1);
    float o[8];
    #pragma unroll
    for (int i = 0; i < 8; i++)
        o[i] = fmaf(scS[q * 8 + i], a[i], dgf * scS[64 + q * 8 + i]);
    uint4 p;
    p.x = pack2h(o[0], o[1]); p.y = pack2h(o[2], o[3]);
    p.z = pack2h(o[4], o[5]); p.w = pack2h(o[6], o[7]);
    *(uint4*)(us + (size_t)r * 64 + q * 8) = p;
}

// Compute scale/shift from stats -> sc (current) + sc5[layer]; zero stats.
__global__ void bn_finalize(
    float* __restrict__ stats, const float* __restrict__ gamma,
    const float* __restrict__ beta, float* __restrict__ sc,
    float* __restrict__ sc5, int layer)
{
    const int c = threadIdx.x; // 64 threads, 1 block
    const float mean = stats[c] * (1.0f / Nn);
    const float var = stats[64 + c] * (1.0f / Nn) - mean * mean;
    const float scale = gamma[layer * 64 + c] * rsqrtf(var + 1e-5f);
    const float shift = beta[layer * 64 + c] - mean * scale;
    sc[c] = scale;
    sc[64 + c] = shift;
    sc5[layer * 128 + c] = scale;
    sc5[layer * 128 + 64 + c] = shift;
    stats[c] = 0.f;
    stats[64 + c] = 0.f;
}

// ---------------------------------------------------------------------------
// Per-graph raw-z column sums (fp16 in, f32 accum). 8 blocks/graph.
// ---------------------------------------------------------------------------
__global__ __launch_bounds__(256) void pool_z(
    const ushort* __restrict__ zs, const int* __restrict__ batch,
    float* __restrict__ poolZ)
{
    const int g = blockIdx.x >> 3;
    const int sub = blockIdx.x & 7;
    const int lo = lower_bound_i(batch, Nn, g);
    const int hi = lower_bound_i(batch, Nn, g + 1);
    const int t = threadIdx.x;
    const int cq = t & 15;                 // cols cq*4 .. +3
    const int rg = (t >> 4) + sub * 16;    // 0..127
    float acc[4] = {};
    for (int row = lo + rg; row < hi; row += 128) {
        const uint2 p = *(const uint2*)(zs + (size_t)row * 64 + cq * 4);
        acc[0] += h2f_lo(p.x); acc[1] += h2f_hi(p.x);
        acc[2] += h2f_lo(p.y); acc[3] += h2f_hi(p.y);
    }
    __shared__ float red[16][16][4];
    #pragma unroll
    for (int i = 0; i < 4; i++) red[t >> 4][cq][i] = acc[i];
    __syncthreads();
    if (t < 64) {
        const int c2 = t >> 2, j = t & 3;
        float s = 0.f;
        #pragma unroll
        for (int r = 0; r < 16; r++) s += red[r][c2][j];
        atomicAdd(&poolZ[g * 64 + c2 * 4 + j], s);
    }
}

// ---------------------------------------------------------------------------
// Final pooled transform across all layers:
// pooled[g][l*64+c] = sc5[l][c]*poolZ[l][g][c] + cnt[g]*sc5[l][64+c]
// ---------------------------------------------------------------------------
__global__ __launch_bounds__(256) void final_pool(
    const float* __restrict__ sc5, const float* __restrict__ poolZ,
    const int* __restrict__ cnt, float* __restrict__ pooled)
{
    const int idx = blockIdx.x * 256 + threadIdx.x; // 40960
    const int c = idx & 63;
    const int g = (idx >> 6) & 127;
    const int l = idx >> 13;
    pooled[g * PDim + l * 64 + c] =
        sc5[l * 128 + c] * poolZ[(size_t)l * Gg * 64 + g * 64 + c]
        + (float)cnt[g] * sc5[l * 128 + 64 + c];
}

// ---------------------------------------------------------------------------
// Proj head GEMM: (128,320)@(320,320)+b (f32, small).
// ---------------------------------------------------------------------------
template<bool RELU>
__global__ __launch_bounds__(256) void proj(
    const float* __restrict__ X, const float* __restrict__ W,
    const float* __restrict__ bias, float* __restrict__ Y)
{
    const int idx = blockIdx.x * 256 + threadIdx.x; // 40960 exact
    const int r = idx / PDim;
    const int c = idx - r * PDim;
    float acc = bias[c];
    #pragma unroll 8
    for (int k = 0; k < PDim; k++)
        acc = fmaf(X[r * PDim + k], W[k * PDim + c], acc);
    if constexpr (RELU) acc = fmaxf(acc, 0.f);
    Y[idx] = acc;
}

// ---------------------------------------------------------------------------
// Row-wise l2 normalize.
// ---------------------------------------------------------------------------
__global__ __launch_bounds__(64) void l2norm_rows(
    const float* __restrict__ X, float* __restrict__ out)
{
    const int r = blockIdx.x;
    const int l = threadIdx.x;
    float v[5];
    float s = 0.f;
    #pragma unroll
    for (int i = 0; i < 5; i++) {
        v[i] = X[r * PDim + i * 64 + l];
        s += v[i] * v[i];
    }
    #pragma unroll
    for (int off = 32; off > 0; off >>= 1) s += __shfl_down(s, off);
    s = __shfl(s, 0);
    const float d = fmaxf(sqrtf(s), 1e-12f);
    #pragma unroll
    for (int i = 0; i < 5; i++)
        out[r * PDim + i * 64 + l] = v[i] / d;
}

// ---------------------------------------------------------------------------
extern "C" void kernel_launch(void* const* d_in, const int* in_sizes, int n_in,
                              void* d_out, int out_size, void* d_ws, size_t ws_size,
                              hipStream_t stream)
{
    const float* x     = (const float*)d_in[0];
    const int*   ei    = (const int*)d_in[1];
    const int*   batch = (const int*)d_in[2];
    const float* Ws    = (const float*)d_in[3];
    const float* bs    = (const float*)d_in[4];
    const float* W1    = (const float*)d_in[5];
    const float* b1    = (const float*)d_in[6];
    const float* W2    = (const float*)d_in[7];
    const float* b2    = (const float*)d_in[8];
    const float* gamma = (const float*)d_in[9];
    const float* beta  = (const float*)d_in[10];
    const float* Wp1   = (const float*)d_in[11];
    const float* bp1   = (const float*)d_in[12];
    const float* Wp2   = (const float*)d_in[13];
    const float* bp2   = (const float*)d_in[14];
    float* out = (float*)d_out;

    // workspace
    ushort* Us = (ushort*)d_ws;                   // u  fp16 (N*64)  12.8MB
    ushort* Zs = Us + (size_t)Nn * 64;            // z  fp16         12.8MB
    ushort* WThi = Zs + (size_t)Nn * 64;          // 11*4096 fp16
    ushort* WTlo = WThi + 11 * 4096;
    float* pooled = (float*)(WTlo + 11 * 4096);   // (G,320)
    float* ytmp   = pooled + (size_t)Gg * PDim;
    float* ypro   = ytmp + (size_t)Gg * PDim;
    float* stats  = ypro + (size_t)Gg * PDim;     // 128
    float* sc     = stats + 128;                  // 128
    float* sc5    = sc + 128;                     // 5*128
    float* poolZ  = sc5 + 5 * 128;                // 5*G*64
    float* spart  = poolZ + 5 * Gg * 64;          // GG*128 (800KB)
    int* cnt    = (int*)(spart + (size_t)GG * 128); // 128
    int* rowptr = cnt + 128;                      // Nn+1
    int* colidx = rowptr + Nn + 1;                // Ee
    int* gCursor = colidx + Ee;                   // 128 (NB used)
    int* bucketBase = gCursor + 128;              // 128
    size_t woff = (size_t)((bucketBase + 128) - (int*)d_ws);
    woff = (woff + 1) & ~(size_t)1;
    uint2* binned = (uint2*)((int*)d_ws + woff);  // NB*BCAP*8B = 12.6MB

    hipMemsetAsync(stats, 0, 128 * sizeof(float), stream);
    hipMemsetAsync(poolZ, 0, 5 * Gg * 64 * sizeof(float), stream);

    init_csr<<<1, 128, 0, stream>>>(batch, gCursor, cnt, sc);
    conv_weights<<<11, 256, 0, stream>>>(Ws, W1, W2, WThi, WTlo);

    // bucketed CSR build
    bin_edges<<<NBLK_A, 256, 0, stream>>>(ei, gCursor, binned);
    scan_buckets<<<1, 128, 0, stream>>>(gCursor, bucketBase);
    build_csr<<<NB, 256, 0, stream>>>(binned, gCursor, bucketBase, rowptr, colidx);

    // encoder: Zs = fp16(x @ Ws + bs)   (raw z_0; BN identity in sc)
    gemm_enc<<<GG, 256, 0, stream>>>(x, WThi, WTlo, bs, Zs);

    for (int l = 0; l < Ll; l++) {
        // u = BN_{l-1} applied to inclusive sum of raw z (affine distributes)
        gather_bn<<<Nn / 32, 256, 0, stream>>>(rowptr, colidx, Zs, sc, Us);
        fused_mlp<<<GG, 256, 0, stream>>>(
            Us,
            WThi + (size_t)(1 + l) * 4096, WTlo + (size_t)(1 + l) * 4096,
            b1 + (size_t)l * 64,
            WThi + (size_t)(6 + l) * 4096, WTlo + (size_t)(6 + l) * 4096,
            b2 + (size_t)l * 64,
            Zs, spart);
        reduce_stats<<<16, 256, 0, stream>>>(spart, stats);
        bn_finalize<<<1, 64, 0, stream>>>(stats, gamma, beta, sc, sc5, l);
        pool_z<<<Gg * 8, 256, 0, stream>>>(Zs, batch, poolZ + (size_t)l * Gg * 64);
    }

    final_pool<<<160, 256, 0, stream>>>(sc5, poolZ, cnt, pooled);

    // proj head (f32)
    proj<true><<<160, 256, 0, stream>>>(pooled, Wp1, bp1, ytmp);
    proj<false><<<160, 256, 0, stream>>>(ytmp, Wp2, bp2, ypro);

    l2norm_rows<<<Gg, 64, 0, stream>>>(ypro, out);               // out0
    l2norm_rows<<<Gg, 64, 0, stream>>>(pooled, out + Gg * PDim); // out1
}